// Round 9
// baseline (330.140 us; speedup 1.0000x reference)
//
#include <hip/hip_runtime.h>
#include <hip/hip_bf16.h>

// Autoregressive LSTM decoder via bf16 MFMA, torch gate order (i,f,g,o).
// B=262144, P=16, H=32, S=25.  One wave = TWO independent 32-batch tiles.
//
// Round-9 change (single variable vs round 8): store experiment.
//  * Projection outputs are buffered one step in dedicated registers; every
//    odd step, BOTH steps' stores issue back-to-back as PLAIN (non-NT)
//    stores.  For even batch rows the 4 adjacent dwordx4 per row fully
//    cover an aligned 128B line (row stride 1600B) -> full-line write
//    combining, less partial-line RFO, fast L2 acks, longer store-reg
//    reuse distance.  Tests the "store-completion floor" hypothesis.
//  * Carried: staggered chains, f32x2 packed EW, k-permutation lane-local
//    B-pack, exp2 scales folded into A, shared-denominator sigmoid*tanh.

constexpr int P = 16;
constexpr int H = 32;
constexpr int S = 25;

typedef short        bf16x8 __attribute__((ext_vector_type(8)));
typedef float        f32x16 __attribute__((ext_vector_type(16)));
typedef float        f32x4  __attribute__((ext_vector_type(4)));
typedef float        f32x2  __attribute__((ext_vector_type(2)));
typedef unsigned int u32x4  __attribute__((ext_vector_type(4)));

union FragU { u32x4 u; bf16x8 b; };

#if __has_builtin(__builtin_amdgcn_exp2f)
#define EX2 __builtin_amdgcn_exp2f
#else
#define EX2 exp2f
#endif

__device__ __forceinline__ unsigned int pkbf(float lo, float hi) {
    unsigned short a = __builtin_bit_cast(unsigned short, __float2bfloat16(lo));
    unsigned short b = __builtin_bit_cast(unsigned short, __float2bfloat16(hi));
    return (unsigned int)a | ((unsigned int)b << 16);
}

// gate-row exp2 scale: rows [0,32)=i, [32,64)=f, [64,96)=g, [96,128)=o
__device__ __forceinline__ float gate_scale(int r) {
    return (r >= 64 && r < 96) ? -2.8853900817779268f   // g rows: -2*log2(e)
                               : -1.4426950408889634f;  // i,f,o rows: -log2(e)
}

// ---------------- setup: build bf16 A-fragments into ws -------------------
// steady W_aug[160][48]: r<128: Wcomb=Whh+Wih*Wout (k<32), bias at k=32, 0 pad;
//                        128<=r<144: Wout rows, bout at k=32; r>=144: 0.
//                        gate rows (r<128) scaled by gate_scale(r).
// step0  W0_aug[128][64]: k<16: Wih; 16<=k<48: Whh; k=48: b_ih+b_hh; 0 pad.
// fragment slot: logical k = 16c + 8*(v>>1) + 4*hi + 2*(v&1) + b
// word index: steady ((t*3+c)*64 + lane)*4 + v   (t<5,c<3)
//             step0  3840 + ((t*4+c)*64 + lane)*4 + v  (t<4,c<4)
__global__ void setup_frags(const float* __restrict__ Wih, const float* __restrict__ Whh,
                            const float* __restrict__ bih, const float* __restrict__ bhh,
                            const float* __restrict__ Wout, const float* __restrict__ bout,
                            unsigned int* __restrict__ ws)
{
    auto waug = [&](int r, int k) -> float {
        float s = (r < 128) ? gate_scale(r) : 1.0f;
        if (r < 128) {
            if (k < 32) {
                float a = Whh[r * H + k];
                for (int p = 0; p < P; ++p) a += Wih[r * P + p] * Wout[p * H + k];
                return s * a;
            }
            if (k == 32) {
                float a = bih[r] + bhh[r];
                for (int p = 0; p < P; ++p) a += Wih[r * P + p] * bout[p];
                return s * a;
            }
            return 0.0f;
        } else if (r < 144) {
            int p = r - 128;
            if (k < 32)  return Wout[p * H + k];
            if (k == 32) return bout[p];
            return 0.0f;
        }
        return 0.0f;
    };
    auto w0aug = [&](int r, int k) -> float {
        float s = gate_scale(r);
        if (k < 16)  return s * Wih[r * P + k];
        if (k < 48)  return s * Whh[r * H + (k - 16)];
        if (k == 48) return s * (bih[r] + bhh[r]);
        return 0.0f;
    };

    const int tid = threadIdx.x;
    for (int idx = tid; idx < 5 * 3 * 64 * 4; idx += 256) {
        int v = idx & 3, l = (idx >> 2) & 63, tc = idx >> 8;
        int t = tc / 3, c = tc % 3;
        int r = 32 * t + (l & 31);
        int k = 16 * c + 8 * (v >> 1) + 4 * (l >> 5) + 2 * (v & 1);
        ws[idx] = pkbf(waug(r, k), waug(r, k + 1));
    }
    for (int idx = tid; idx < 4 * 4 * 64 * 4; idx += 256) {
        int v = idx & 3, l = (idx >> 2) & 63, tc = idx >> 8;
        int t = tc / 4, c = tc % 4;
        int r = 32 * t + (l & 31);
        int k = 16 * c + 8 * (v >> 1) + 4 * (l >> 5) + 2 * (v & 1);
        ws[3840 + idx] = pkbf(w0aug(r, k), w0aug(r, k + 1));
    }
}

// ------------------------------- main -------------------------------------
__global__ __launch_bounds__(256, 2) void decoder_mfma(
    const float* __restrict__ x0, const float* __restrict__ h0,
    const float* __restrict__ c0, const unsigned int* __restrict__ ws,
    float* __restrict__ out, int batch)
{
    const int lane = threadIdx.x & 63;
    const int wid  = threadIdx.x >> 6;
    const int bcol = lane & 31;
    const int hi   = lane >> 5;
    const int base = (blockIdx.x * 4 + wid) * 64;   // 64 batch rows per wave
    const int bg0  = base + bcol;
    const int bg1  = base + 32 + bcol;
    if (bg1 >= batch) return;  // batch % 256 == 0: wave-uniform

    // steady A-fragments: 5 tiles (4 gate quarters + proj) x 3 K-chunks
    FragU A[5][3];
    #pragma unroll
    for (int t = 0; t < 5; ++t)
        #pragma unroll
        for (int c = 0; c < 3; ++c)
            A[t][c].u = *reinterpret_cast<const u32x4*>(ws + ((t * 3 + c) * 64 + lane) * 4);

    // bias B-chunk: logical k=32 (steady) / k=48 (step0) at (hi=0, v=0, lo half)
    FragU Bbias;
    Bbias.u.x = (hi == 0) ? 0x3F80u : 0u;  // bf16(1.0)
    Bbias.u.y = 0u; Bbias.u.z = 0u; Bbias.u.w = 0u;

    // cell state in D-layout pairs: cc[i] = (c[row(2i)], c[row(2i+1)])
    f32x2 cc0[8], cc1[8];
    #pragma unroll
    for (int q = 0; q < 4; ++q) {
        f32x4 t0 = *reinterpret_cast<const f32x4*>(c0 + (size_t)bg0 * H + q * 8 + 4 * hi);
        cc0[2 * q]     = f32x2{t0.x, t0.y};
        cc0[2 * q + 1] = f32x2{t0.z, t0.w};
        f32x4 t1 = *reinterpret_cast<const f32x4*>(c0 + (size_t)bg1 * H + q * 8 + 4 * hi);
        cc1[2 * q]     = f32x2{t1.x, t1.y};
        cc1[2 * q + 1] = f32x2{t1.z, t1.w};
    }

    const f32x16 vzero = {};
    f32x16 acc0[4], acc1[4];

    // ---------------- helper phases (all compile-time indexed) ------------
    auto EW = [&](f32x16 (&acc)[4], f32x2 (&cc)[8], f32x2 (&hh)[8]) {
        const f32x2 one = {1.0f, 1.0f};
        const f32x2 nk2 = {-2.8853900817779268f, -2.8853900817779268f};
        #pragma unroll
        for (int i = 0; i < 8; ++i) {
            f32x2 Fi = {acc[0][2 * i], acc[0][2 * i + 1]};
            f32x2 Ff = {acc[1][2 * i], acc[1][2 * i + 1]};
            f32x2 Fg = {acc[2][2 * i], acc[2][2 * i + 1]};
            f32x2 Fo = {acc[3][2 * i], acc[3][2 * i + 1]};
            f32x2 ei, ef, eg, eo;
            ei.x = EX2(Fi.x); ei.y = EX2(Fi.y);      // e^{-i}
            ef.x = EX2(Ff.x); ef.y = EX2(Ff.y);      // e^{-f}
            eg.x = EX2(Fg.x); eg.y = EX2(Fg.y);      // e^{-2g}
            eo.x = EX2(Fo.x); eo.y = EX2(Fo.y);      // e^{-o}
            f32x2 d1 = (one + ei) * (one + eg);
            f32x2 r1; r1.x = __builtin_amdgcn_rcpf(d1.x); r1.y = __builtin_amdgcn_rcpf(d1.y);
            f32x2 tg = (one - eg) * r1;              // sig(i)*tanh(g)
            f32x2 df = one + ef;
            f32x2 rf; rf.x = __builtin_amdgcn_rcpf(df.x); rf.y = __builtin_amdgcn_rcpf(df.y);
            f32x2 cn = cc[i] * rf + tg;              // pk_fma
            cc[i] = cn;
            f32x2 ar = cn * nk2;
            f32x2 ec; ec.x = EX2(ar.x); ec.y = EX2(ar.y);   // e^{-2cn}
            f32x2 d2 = (one + ec) * (one + eo);
            f32x2 r2; r2.x = __builtin_amdgcn_rcpf(d2.x); r2.y = __builtin_amdgcn_rcpf(d2.y);
            hh[i] = (one - ec) * r2;                 // sig(o)*tanh(cn)
        }
    };
    auto PACK = [&](f32x2 (&hh)[8], FragU (&Bh)[2]) {
        Bh[0].u.x = pkbf(hh[0].x, hh[0].y); Bh[0].u.y = pkbf(hh[1].x, hh[1].y);
        Bh[0].u.z = pkbf(hh[2].x, hh[2].y); Bh[0].u.w = pkbf(hh[3].x, hh[3].y);
        Bh[1].u.x = pkbf(hh[4].x, hh[4].y); Bh[1].u.y = pkbf(hh[5].x, hh[5].y);
        Bh[1].u.z = pkbf(hh[6].x, hh[6].y); Bh[1].u.w = pkbf(hh[7].x, hh[7].y);
    };
    auto PROJ = [&](FragU (&Bh)[2], f32x4& v0, f32x4& v1) {
        f32x16 px;
        px = __builtin_amdgcn_mfma_f32_32x32x16_bf16(A[4][2].b, Bbias.b, vzero, 0, 0, 0);
        px = __builtin_amdgcn_mfma_f32_32x32x16_bf16(A[4][0].b, Bh[0].b, px,    0, 0, 0);
        px = __builtin_amdgcn_mfma_f32_32x32x16_bf16(A[4][1].b, Bh[1].b, px,    0, 0, 0);
        v0 = f32x4{px[0], px[1], px[2], px[3]};
        v1 = f32x4{px[4], px[5], px[6], px[7]};
    };
    auto GATES = [&](f32x16 (&acc)[4], FragU (&Bh)[2]) {
        #pragma unroll
        for (int t = 0; t < 4; ++t) {
            f32x16 a;
            a = __builtin_amdgcn_mfma_f32_32x32x16_bf16(A[t][2].b, Bbias.b, vzero, 0, 0, 0);
            a = __builtin_amdgcn_mfma_f32_32x32x16_bf16(A[t][0].b, Bh[0].b, a,    0, 0, 0);
            a = __builtin_amdgcn_mfma_f32_32x32x16_bf16(A[t][1].b, Bh[1].b, a,    0, 0, 0);
            acc[t] = a;
        }
    };

    // ---- step-0 gates: K = [x0(16) | h0(32) | 1], W0_aug fragments ----
    {
        FragU B00[4], B01[4];
        {
            const float* p = x0 + (size_t)bg0 * P;
            f32x4 a  = *reinterpret_cast<const f32x4*>(p + 4 * hi);
            f32x4 b4 = *reinterpret_cast<const f32x4*>(p + 8 + 4 * hi);
            B00[0].u.x = pkbf(a.x, a.y);   B00[0].u.y = pkbf(a.z, a.w);
            B00[0].u.z = pkbf(b4.x, b4.y); B00[0].u.w = pkbf(b4.z, b4.w);
            p = x0 + (size_t)bg1 * P;
            a  = *reinterpret_cast<const f32x4*>(p + 4 * hi);
            b4 = *reinterpret_cast<const f32x4*>(p + 8 + 4 * hi);
            B01[0].u.x = pkbf(a.x, a.y);   B01[0].u.y = pkbf(a.z, a.w);
            B01[0].u.z = pkbf(b4.x, b4.y); B01[0].u.w = pkbf(b4.z, b4.w);
        }
        #pragma unroll
        for (int ch = 0; ch < 2; ++ch) {
            const float* q = h0 + (size_t)bg0 * H + 16 * ch;
            f32x4 c4 = *reinterpret_cast<const f32x4*>(q + 4 * hi);
            f32x4 d4 = *reinterpret_cast<const f32x4*>(q + 8 + 4 * hi);
            B00[1 + ch].u.x = pkbf(c4.x, c4.y); B00[1 + ch].u.y = pkbf(c4.z, c4.w);
            B00[1 + ch].u.z = pkbf(d4.x, d4.y); B00[1 + ch].u.w = pkbf(d4.z, d4.w);
            q = h0 + (size_t)bg1 * H + 16 * ch;
            c4 = *reinterpret_cast<const f32x4*>(q + 4 * hi);
            d4 = *reinterpret_cast<const f32x4*>(q + 8 + 4 * hi);
            B01[1 + ch].u.x = pkbf(c4.x, c4.y); B01[1 + ch].u.y = pkbf(c4.z, c4.w);
            B01[1 + ch].u.z = pkbf(d4.x, d4.y); B01[1 + ch].u.w = pkbf(d4.z, d4.w);
        }
        B00[3] = Bbias; B01[3] = Bbias;
        #pragma unroll
        for (int t = 0; t < 4; ++t) { acc0[t] = vzero; acc1[t] = vzero; }
        #pragma unroll
        for (int c4 = 0; c4 < 4; ++c4)
            #pragma unroll
            for (int t = 0; t < 4; ++t) {
                FragU a;  // shared between both tiles
                a.u = *reinterpret_cast<const u32x4*>(ws + 3840 + ((t * 4 + c4) * 64 + lane) * 4);
                acc0[t] = __builtin_amdgcn_mfma_f32_32x32x16_bf16(a.b, B00[c4].b, acc0[t], 0, 0, 0);
                acc1[t] = __builtin_amdgcn_mfma_f32_32x32x16_bf16(a.b, B01[c4].b, acc1[t], 0, 0, 0);
            }
    }

    // per-tile previous-step projection buffers (dedicated regs, 2-step reuse)
    f32x4 p0v0, p0v1, p1v0, p1v1;

    float* const o0 = out + (size_t)bg0 * (S * P) + 4 * hi;
    float* const o1 = out + (size_t)bg1 * (S * P) + 4 * hi;

    // ---- steady loop: staggered chains, paired 2-step stores ----
    for (int s = 0; s < S; ++s) {
        // phase A: elementwise + pack, tile 0
        f32x2 hh0[8]; FragU Bh0[2];
        EW(acc0, cc0, hh0); PACK(hh0, Bh0);
        // phase B: MFMA block tile 0 (proj + next gates)
        f32x4 cv0, cv1;
        PROJ(Bh0, cv0, cv1);
        if (s & 1) {
            // both steps' 4 stores back-to-back: full 128B line per even row
            *reinterpret_cast<f32x4*>(o0 + (s - 1) * P)      = p0v0;
            *reinterpret_cast<f32x4*>(o0 + (s - 1) * P + 8)  = p0v1;
            *reinterpret_cast<f32x4*>(o0 + s * P)            = cv0;
            *reinterpret_cast<f32x4*>(o0 + s * P + 8)        = cv1;
        } else { p0v0 = cv0; p0v1 = cv1; }
        if (s + 1 < S) GATES(acc0, Bh0);
        // phase C: elementwise + pack, tile 1
        f32x2 hh1[8]; FragU Bh1[2];
        EW(acc1, cc1, hh1); PACK(hh1, Bh1);
        // phase D: MFMA block tile 1
        PROJ(Bh1, cv0, cv1);
        if (s & 1) {
            *reinterpret_cast<f32x4*>(o1 + (s - 1) * P)      = p1v0;
            *reinterpret_cast<f32x4*>(o1 + (s - 1) * P + 8)  = p1v1;
            *reinterpret_cast<f32x4*>(o1 + s * P)            = cv0;
            *reinterpret_cast<f32x4*>(o1 + s * P + 8)        = cv1;
        } else { p1v0 = cv0; p1v1 = cv1; }
        if (s + 1 < S) GATES(acc1, Bh1);
    }
    // tail: step 24 (even) buffered, never stored in-loop
    *reinterpret_cast<f32x4*>(o0 + (S - 1) * P)     = p0v0;
    *reinterpret_cast<f32x4*>(o0 + (S - 1) * P + 8) = p0v1;
    *reinterpret_cast<f32x4*>(o1 + (S - 1) * P)     = p1v0;
    *reinterpret_cast<f32x4*>(o1 + (S - 1) * P + 8) = p1v1;
}

extern "C" void kernel_launch(void* const* d_in, const int* in_sizes, int n_in,
                              void* d_out, int out_size, void* d_ws, size_t ws_size,
                              hipStream_t stream) {
    const float* x0   = (const float*)d_in[0];
    const float* h0   = (const float*)d_in[1];
    const float* c0   = (const float*)d_in[2];
    const float* Wih  = (const float*)d_in[3];
    const float* Whh  = (const float*)d_in[4];
    const float* bih  = (const float*)d_in[5];
    const float* bhh  = (const float*)d_in[6];
    const float* Wout = (const float*)d_in[7];
    const float* bout = (const float*)d_in[8];
    float* out = (float*)d_out;
    unsigned int* ws = (unsigned int*)d_ws;

    const int batch = in_sizes[0] / P;  // 262144

    hipLaunchKernelGGL(setup_frags, dim3(1), dim3(256), 0, stream,
                       Wih, Whh, bih, bhh, Wout, bout, ws);

    dim3 block(256);                    // 4 waves x 64 batch rows = 256 batch/block
    dim3 grid((batch + 255) / 256);     // 1024 blocks
    hipLaunchKernelGGL(decoder_mfma, grid, block, 0, stream,
                       x0, h0, c0, ws, out, batch);
}

// Round 10
// 323.932 us; speedup vs baseline: 1.0192x; 1.0192x over previous
//
#include <hip/hip_runtime.h>
#include <hip/hip_bf16.h>

// Autoregressive LSTM decoder via bf16 MFMA, torch gate order (i,f,g,o).
// B=262144, P=16, H=32, S=25.  One wave = TWO independent 32-batch tiles.
//
// Round-10 structure:
//  * NO transcendentals in the hot loop: tanh via continued-fraction Pade
//    tanh(x) ~ x(945+105t+t^2)/(945+420t+15t^2), t=x^2, |x| clamped to 3.75.
//    sigmoid(x) = (1+tanh(x/2))/2 with the /2 folded into the A-matrix
//    (i,f,o gate rows scaled 0.5; g rows 1.0).  Shared denominators keep
//    2 rcp / element, 0 exp (was 5 exp + 3 rcp) -> cuts trans issue ~4x.
//  * Stores: per-step NT dwordx4 (round 9 proved plain stores regress).
//  * Carried: staggered chains, f32x2 packed EW, k-permutation lane-local
//    B-pack (no cross-lane ops), combined-weight fusion.

constexpr int P = 16;
constexpr int H = 32;
constexpr int S = 25;

typedef short        bf16x8 __attribute__((ext_vector_type(8)));
typedef float        f32x16 __attribute__((ext_vector_type(16)));
typedef float        f32x4  __attribute__((ext_vector_type(4)));
typedef float        f32x2  __attribute__((ext_vector_type(2)));
typedef unsigned int u32x4  __attribute__((ext_vector_type(4)));

union FragU { u32x4 u; bf16x8 b; };

__device__ __forceinline__ unsigned int pkbf(float lo, float hi) {
    unsigned short a = __builtin_bit_cast(unsigned short, __float2bfloat16(lo));
    unsigned short b = __builtin_bit_cast(unsigned short, __float2bfloat16(hi));
    return (unsigned int)a | ((unsigned int)b << 16);
}

// gate-row scale: i,f,o rows 0.5 (sigmoid half-arg), g rows 1.0 (tanh)
__device__ __forceinline__ float gate_scale(int r) {
    return (r >= 64 && r < 96) ? 1.0f : 0.5f;
}

// ---------------- setup: build bf16 A-fragments into ws -------------------
// steady W_aug[160][48]: r<128: Wcomb=Whh+Wih*Wout (k<32), bias at k=32, 0 pad;
//                        128<=r<144: Wout rows, bout at k=32; r>=144: 0.
//                        gate rows (r<128) scaled by gate_scale(r).
// step0  W0_aug[128][64]: k<16: Wih; 16<=k<48: Whh; k=48: b_ih+b_hh; 0 pad.
// fragment slot: logical k = 16c + 8*(v>>1) + 4*hi + 2*(v&1) + b
// word index: steady ((t*3+c)*64 + lane)*4 + v   (t<5,c<3)
//             step0  3840 + ((t*4+c)*64 + lane)*4 + v  (t<4,c<4)
__global__ void setup_frags(const float* __restrict__ Wih, const float* __restrict__ Whh,
                            const float* __restrict__ bih, const float* __restrict__ bhh,
                            const float* __restrict__ Wout, const float* __restrict__ bout,
                            unsigned int* __restrict__ ws)
{
    auto waug = [&](int r, int k) -> float {
        float s = (r < 128) ? gate_scale(r) : 1.0f;
        if (r < 128) {
            if (k < 32) {
                float a = Whh[r * H + k];
                for (int p = 0; p < P; ++p) a += Wih[r * P + p] * Wout[p * H + k];
                return s * a;
            }
            if (k == 32) {
                float a = bih[r] + bhh[r];
                for (int p = 0; p < P; ++p) a += Wih[r * P + p] * bout[p];
                return s * a;
            }
            return 0.0f;
        } else if (r < 144) {
            int p = r - 128;
            if (k < 32)  return Wout[p * H + k];
            if (k == 32) return bout[p];
            return 0.0f;
        }
        return 0.0f;
    };
    auto w0aug = [&](int r, int k) -> float {
        float s = gate_scale(r);
        if (k < 16)  return s * Wih[r * P + k];
        if (k < 48)  return s * Whh[r * H + (k - 16)];
        if (k == 48) return s * (bih[r] + bhh[r]);
        return 0.0f;
    };

    const int tid = threadIdx.x;
    for (int idx = tid; idx < 5 * 3 * 64 * 4; idx += 256) {
        int v = idx & 3, l = (idx >> 2) & 63, tc = idx >> 8;
        int t = tc / 3, c = tc % 3;
        int r = 32 * t + (l & 31);
        int k = 16 * c + 8 * (v >> 1) + 4 * (l >> 5) + 2 * (v & 1);
        ws[idx] = pkbf(waug(r, k), waug(r, k + 1));
    }
    for (int idx = tid; idx < 4 * 4 * 64 * 4; idx += 256) {
        int v = idx & 3, l = (idx >> 2) & 63, tc = idx >> 8;
        int t = tc / 4, c = tc % 4;
        int r = 32 * t + (l & 31);
        int k = 16 * c + 8 * (v >> 1) + 4 * (l >> 5) + 2 * (v & 1);
        ws[3840 + idx] = pkbf(w0aug(r, k), w0aug(r, k + 1));
    }
}

// ------------------------------- main -------------------------------------
__global__ __launch_bounds__(256, 2) void decoder_mfma(
    const float* __restrict__ x0, const float* __restrict__ h0,
    const float* __restrict__ c0, const unsigned int* __restrict__ ws,
    float* __restrict__ out, int batch)
{
    const int lane = threadIdx.x & 63;
    const int wid  = threadIdx.x >> 6;
    const int bcol = lane & 31;
    const int hi   = lane >> 5;
    const int base = (blockIdx.x * 4 + wid) * 64;   // 64 batch rows per wave
    const int bg0  = base + bcol;
    const int bg1  = base + 32 + bcol;
    if (bg1 >= batch) return;  // batch % 256 == 0: wave-uniform

    // steady A-fragments: 5 tiles (4 gate quarters + proj) x 3 K-chunks
    FragU A[5][3];
    #pragma unroll
    for (int t = 0; t < 5; ++t)
        #pragma unroll
        for (int c = 0; c < 3; ++c)
            A[t][c].u = *reinterpret_cast<const u32x4*>(ws + ((t * 3 + c) * 64 + lane) * 4);

    // bias B-chunk: logical k=32 (steady) / k=48 (step0) at (hi=0, v=0, lo half)
    FragU Bbias;
    Bbias.u.x = (hi == 0) ? 0x3F80u : 0u;  // bf16(1.0)
    Bbias.u.y = 0u; Bbias.u.z = 0u; Bbias.u.w = 0u;

    // cell state in D-layout pairs: cc[i] = (c[row(2i)], c[row(2i+1)])
    f32x2 cc0[8], cc1[8];
    #pragma unroll
    for (int q = 0; q < 4; ++q) {
        f32x4 t0 = *reinterpret_cast<const f32x4*>(c0 + (size_t)bg0 * H + q * 8 + 4 * hi);
        cc0[2 * q]     = f32x2{t0.x, t0.y};
        cc0[2 * q + 1] = f32x2{t0.z, t0.w};
        f32x4 t1 = *reinterpret_cast<const f32x4*>(c0 + (size_t)bg1 * H + q * 8 + 4 * hi);
        cc1[2 * q]     = f32x2{t1.x, t1.y};
        cc1[2 * q + 1] = f32x2{t1.z, t1.w};
    }

    const f32x16 vzero = {};
    f32x16 acc0[4], acc1[4];

    // ---------------- helper phases (all compile-time indexed) ------------
    // CF9 Pade tanh pieces: n(y)=y*(945+105t+t^2), d(y)=945+420t+15t^2, t=y^2
    auto act = [&](f32x2 y, f32x2& n, f32x2& d) {
        const f32x2 cmax = { 3.75f,  3.75f};
        const f32x2 cmin = {-3.75f, -3.75f};
        f32x2 m = __builtin_elementwise_min(__builtin_elementwise_max(y, cmin), cmax);
        f32x2 t = m * m;
        const f32x2 k105 = {105.0f, 105.0f};
        const f32x2 k945 = {945.0f, 945.0f};
        const f32x2 k420 = {420.0f, 420.0f};
        const f32x2 k15  = {15.0f, 15.0f};
        n = ((t + k105) * t + k945) * m;
        d = (k15 * t + k420) * t + k945;
    };
    auto EW = [&](f32x16 (&acc)[4], f32x2 (&cc)[8], f32x2 (&hh)[8]) {
        const f32x2 half = {0.5f, 0.5f};
        #pragma unroll
        for (int i = 0; i < 8; ++i) {
            f32x2 Yi = {acc[0][2 * i], acc[0][2 * i + 1]};   // i/2
            f32x2 Yf = {acc[1][2 * i], acc[1][2 * i + 1]};   // f/2
            f32x2 Yg = {acc[2][2 * i], acc[2][2 * i + 1]};   // g
            f32x2 Yo = {acc[3][2 * i], acc[3][2 * i + 1]};   // o/2
            f32x2 ni, di, nf, df, ng, dg, no, dо;
            act(Yi, ni, di); act(Yf, nf, df); act(Yg, ng, dg); act(Yo, no, dо);
            // cn = [c(df+nf)*di*dg + (di+ni)*ng*df] / (2 df di dg)
            f32x2 sf = df + nf;
            f32x2 si = di + ni;
            f32x2 Pd = di * dg;
            f32x2 t1 = cc[i] * sf * Pd;
            f32x2 t2 = si * ng * df;
            f32x2 num = t1 + t2;
            f32x2 den = df * Pd;
            f32x2 r; r.x = __builtin_amdgcn_rcpf(den.x); r.y = __builtin_amdgcn_rcpf(den.y);
            f32x2 cn = num * (r * half);
            cc[i] = cn;
            // h = (do+no)*nc / (2 do dc)
            f32x2 nc, dc;
            act(cn, nc, dc);
            f32x2 so = dо + no;
            f32x2 numh = so * nc;
            f32x2 denh = dо * dc;
            f32x2 rh; rh.x = __builtin_amdgcn_rcpf(denh.x); rh.y = __builtin_amdgcn_rcpf(denh.y);
            hh[i] = numh * (rh * half);
        }
    };
    auto PACK = [&](f32x2 (&hh)[8], FragU (&Bh)[2]) {
        Bh[0].u.x = pkbf(hh[0].x, hh[0].y); Bh[0].u.y = pkbf(hh[1].x, hh[1].y);
        Bh[0].u.z = pkbf(hh[2].x, hh[2].y); Bh[0].u.w = pkbf(hh[3].x, hh[3].y);
        Bh[1].u.x = pkbf(hh[4].x, hh[4].y); Bh[1].u.y = pkbf(hh[5].x, hh[5].y);
        Bh[1].u.z = pkbf(hh[6].x, hh[6].y); Bh[1].u.w = pkbf(hh[7].x, hh[7].y);
    };
    auto PROJSTORE = [&](FragU (&Bh)[2], int bg, int s) {
        f32x16 px;
        px = __builtin_amdgcn_mfma_f32_32x32x16_bf16(A[4][2].b, Bbias.b, vzero, 0, 0, 0);
        px = __builtin_amdgcn_mfma_f32_32x32x16_bf16(A[4][0].b, Bh[0].b, px,    0, 0, 0);
        px = __builtin_amdgcn_mfma_f32_32x32x16_bf16(A[4][1].b, Bh[1].b, px,    0, 0, 0);
        float* op = out + ((size_t)bg * S + s) * P + 4 * hi;
        f32x4 v0 = {px[0], px[1], px[2], px[3]};
        f32x4 v1 = {px[4], px[5], px[6], px[7]};
        __builtin_nontemporal_store(v0, reinterpret_cast<f32x4*>(op));
        __builtin_nontemporal_store(v1, reinterpret_cast<f32x4*>(op + 8));
    };
    auto GATES = [&](f32x16 (&acc)[4], FragU (&Bh)[2]) {
        #pragma unroll
        for (int t = 0; t < 4; ++t) {
            f32x16 a;
            a = __builtin_amdgcn_mfma_f32_32x32x16_bf16(A[t][2].b, Bbias.b, vzero, 0, 0, 0);
            a = __builtin_amdgcn_mfma_f32_32x32x16_bf16(A[t][0].b, Bh[0].b, a,    0, 0, 0);
            a = __builtin_amdgcn_mfma_f32_32x32x16_bf16(A[t][1].b, Bh[1].b, a,    0, 0, 0);
            acc[t] = a;
        }
    };

    // ---- step-0 gates: K = [x0(16) | h0(32) | 1], W0_aug fragments ----
    {
        FragU B00[4], B01[4];
        {
            const float* p = x0 + (size_t)bg0 * P;
            f32x4 a  = *reinterpret_cast<const f32x4*>(p + 4 * hi);
            f32x4 b4 = *reinterpret_cast<const f32x4*>(p + 8 + 4 * hi);
            B00[0].u.x = pkbf(a.x, a.y);   B00[0].u.y = pkbf(a.z, a.w);
            B00[0].u.z = pkbf(b4.x, b4.y); B00[0].u.w = pkbf(b4.z, b4.w);
            p = x0 + (size_t)bg1 * P;
            a  = *reinterpret_cast<const f32x4*>(p + 4 * hi);
            b4 = *reinterpret_cast<const f32x4*>(p + 8 + 4 * hi);
            B01[0].u.x = pkbf(a.x, a.y);   B01[0].u.y = pkbf(a.z, a.w);
            B01[0].u.z = pkbf(b4.x, b4.y); B01[0].u.w = pkbf(b4.z, b4.w);
        }
        #pragma unroll
        for (int ch = 0; ch < 2; ++ch) {
            const float* q = h0 + (size_t)bg0 * H + 16 * ch;
            f32x4 c4 = *reinterpret_cast<const f32x4*>(q + 4 * hi);
            f32x4 d4 = *reinterpret_cast<const f32x4*>(q + 8 + 4 * hi);
            B00[1 + ch].u.x = pkbf(c4.x, c4.y); B00[1 + ch].u.y = pkbf(c4.z, c4.w);
            B00[1 + ch].u.z = pkbf(d4.x, d4.y); B00[1 + ch].u.w = pkbf(d4.z, d4.w);
            q = h0 + (size_t)bg1 * H + 16 * ch;
            c4 = *reinterpret_cast<const f32x4*>(q + 4 * hi);
            d4 = *reinterpret_cast<const f32x4*>(q + 8 + 4 * hi);
            B01[1 + ch].u.x = pkbf(c4.x, c4.y); B01[1 + ch].u.y = pkbf(c4.z, c4.w);
            B01[1 + ch].u.z = pkbf(d4.x, d4.y); B01[1 + ch].u.w = pkbf(d4.z, d4.w);
        }
        B00[3] = Bbias; B01[3] = Bbias;
        #pragma unroll
        for (int t = 0; t < 4; ++t) { acc0[t] = vzero; acc1[t] = vzero; }
        #pragma unroll
        for (int c4 = 0; c4 < 4; ++c4)
            #pragma unroll
            for (int t = 0; t < 4; ++t) {
                FragU a;  // shared between both tiles
                a.u = *reinterpret_cast<const u32x4*>(ws + 3840 + ((t * 4 + c4) * 64 + lane) * 4);
                acc0[t] = __builtin_amdgcn_mfma_f32_32x32x16_bf16(a.b, B00[c4].b, acc0[t], 0, 0, 0);
                acc1[t] = __builtin_amdgcn_mfma_f32_32x32x16_bf16(a.b, B01[c4].b, acc1[t], 0, 0, 0);
            }
    }

    // ---- steady loop: staggered chains, per-step NT stores ----
    for (int s = 0; s < S; ++s) {
        // phase A: elementwise + pack, tile 0
        f32x2 hh0[8]; FragU Bh0[2];
        EW(acc0, cc0, hh0); PACK(hh0, Bh0);
        // phase B: MFMA block tile 0 (proj + next gates)
        PROJSTORE(Bh0, bg0, s);
        if (s + 1 < S) GATES(acc0, Bh0);
        // phase C: elementwise + pack, tile 1
        f32x2 hh1[8]; FragU Bh1[2];
        EW(acc1, cc1, hh1); PACK(hh1, Bh1);
        // phase D: MFMA block tile 1
        PROJSTORE(Bh1, bg1, s);
        if (s + 1 < S) GATES(acc1, Bh1);
    }
}

extern "C" void kernel_launch(void* const* d_in, const int* in_sizes, int n_in,
                              void* d_out, int out_size, void* d_ws, size_t ws_size,
                              hipStream_t stream) {
    const float* x0   = (const float*)d_in[0];
    const float* h0   = (const float*)d_in[1];
    const float* c0   = (const float*)d_in[2];
    const float* Wih  = (const float*)d_in[3];
    const float* Whh  = (const float*)d_in[4];
    const float* bih  = (const float*)d_in[5];
    const float* bhh  = (const float*)d_in[6];
    const float* Wout = (const float*)d_in[7];
    const float* bout = (const float*)d_in[8];
    float* out = (float*)d_out;
    unsigned int* ws = (unsigned int*)d_ws;

    const int batch = in_sizes[0] / P;  // 262144

    hipLaunchKernelGGL(setup_frags, dim3(1), dim3(256), 0, stream,
                       Wih, Whh, bih, bhh, Wout, bout, ws);

    dim3 block(256);                    // 4 waves x 64 batch rows = 256 batch/block
    dim3 grid((batch + 255) / 256);     // 1024 blocks
    hipLaunchKernelGGL(decoder_mfma, grid, block, 0, stream,
                       x0, h0, c0, ws, out, batch);
}

// Round 11
// 226.040 us; speedup vs baseline: 1.4605x; 1.4331x over previous
//
#include <hip/hip_runtime.h>
#include <hip/hip_bf16.h>

// Autoregressive LSTM decoder via bf16 MFMA, torch gate order (i,f,g,o).
// B=262144, P=16, H=32, S=25.  One wave = 32 batch rows (round-6 base).
//
// Round-11 change (single variable vs round 6): 4-step NT store batching.
//  * Projection outputs buffered in 8 dedicated f32x4 regs; every 4th step
//    flush 8 NT stores -> per row a contiguous 256B run (steps are adjacent
//    in [B][S][P]).  Tests the ~2 TB/s scattered-64B write-drain theory.
//  * Stores remain NONTEMPORAL (round 9 proved plain stores add RFO).
//  * Carried from r5/6: k-permutation lane-local B-pack, exp2 scales folded
//    into A, shared-denominator sigmoid*tanh (5 exp + 3 rcp / elem).

constexpr int P = 16;
constexpr int H = 32;
constexpr int S = 25;

typedef short        bf16x8 __attribute__((ext_vector_type(8)));
typedef float        f32x16 __attribute__((ext_vector_type(16)));
typedef float        f32x4  __attribute__((ext_vector_type(4)));
typedef unsigned int u32x4  __attribute__((ext_vector_type(4)));

union FragU { u32x4 u; bf16x8 b; };

#if __has_builtin(__builtin_amdgcn_exp2f)
#define EX2 __builtin_amdgcn_exp2f
#else
#define EX2 exp2f
#endif

__device__ __forceinline__ unsigned int pkbf(float lo, float hi) {
    unsigned short a = __builtin_bit_cast(unsigned short, __float2bfloat16(lo));
    unsigned short b = __builtin_bit_cast(unsigned short, __float2bfloat16(hi));
    return (unsigned int)a | ((unsigned int)b << 16);
}

// gate-row exp2 scale: rows [0,32)=i, [32,64)=f, [64,96)=g, [96,128)=o
__device__ __forceinline__ float gate_scale(int r) {
    return (r >= 64 && r < 96) ? -2.8853900817779268f   // g rows: -2*log2(e)
                               : -1.4426950408889634f;  // i,f,o rows: -log2(e)
}

// ---------------- setup: build bf16 A-fragments into ws -------------------
// steady W_aug[160][48]: r<128: Wcomb=Whh+Wih*Wout (k<32), bias at k=32, 0 pad;
//                        128<=r<144: Wout rows, bout at k=32; r>=144: 0.
//                        gate rows (r<128) scaled by gate_scale(r).
// step0  W0_aug[128][64]: k<16: Wih; 16<=k<48: Whh; k=48: b_ih+b_hh; 0 pad.
// fragment slot: logical k = 16c + 8*(v>>1) + 4*hi + 2*(v&1) + b
// word index: steady ((t*3+c)*64 + lane)*4 + v   (t<5,c<3)
//             step0  3840 + ((t*4+c)*64 + lane)*4 + v  (t<4,c<4)
__global__ void setup_frags(const float* __restrict__ Wih, const float* __restrict__ Whh,
                            const float* __restrict__ bih, const float* __restrict__ bhh,
                            const float* __restrict__ Wout, const float* __restrict__ bout,
                            unsigned int* __restrict__ ws)
{
    auto waug = [&](int r, int k) -> float {
        float s = (r < 128) ? gate_scale(r) : 1.0f;
        if (r < 128) {
            if (k < 32) {
                float a = Whh[r * H + k];
                for (int p = 0; p < P; ++p) a += Wih[r * P + p] * Wout[p * H + k];
                return s * a;
            }
            if (k == 32) {
                float a = bih[r] + bhh[r];
                for (int p = 0; p < P; ++p) a += Wih[r * P + p] * bout[p];
                return s * a;
            }
            return 0.0f;
        } else if (r < 144) {
            int p = r - 128;
            if (k < 32)  return Wout[p * H + k];
            if (k == 32) return bout[p];
            return 0.0f;
        }
        return 0.0f;
    };
    auto w0aug = [&](int r, int k) -> float {
        float s = gate_scale(r);
        if (k < 16)  return s * Wih[r * P + k];
        if (k < 48)  return s * Whh[r * H + (k - 16)];
        if (k == 48) return s * (bih[r] + bhh[r]);
        return 0.0f;
    };

    const int tid = threadIdx.x;
    for (int idx = tid; idx < 5 * 3 * 64 * 4; idx += 256) {
        int v = idx & 3, l = (idx >> 2) & 63, tc = idx >> 8;
        int t = tc / 3, c = tc % 3;
        int r = 32 * t + (l & 31);
        int k = 16 * c + 8 * (v >> 1) + 4 * (l >> 5) + 2 * (v & 1);
        ws[idx] = pkbf(waug(r, k), waug(r, k + 1));
    }
    for (int idx = tid; idx < 4 * 4 * 64 * 4; idx += 256) {
        int v = idx & 3, l = (idx >> 2) & 63, tc = idx >> 8;
        int t = tc / 4, c = tc % 4;
        int r = 32 * t + (l & 31);
        int k = 16 * c + 8 * (v >> 1) + 4 * (l >> 5) + 2 * (v & 1);
        ws[3840 + idx] = pkbf(w0aug(r, k), w0aug(r, k + 1));
    }
}

// ------------------------------- main -------------------------------------
__global__ __launch_bounds__(256, 2) void decoder_mfma(
    const float* __restrict__ x0, const float* __restrict__ h0,
    const float* __restrict__ c0, const unsigned int* __restrict__ ws,
    float* __restrict__ out, int batch)
{
    const int lane = threadIdx.x & 63;
    const int wid  = threadIdx.x >> 6;
    const int bcol = lane & 31;
    const int hi   = lane >> 5;
    const int bg   = (blockIdx.x * 4 + wid) * 32 + bcol;  // this lane's batch row
    if (bg >= batch) return;  // batch % 128 == 0: wave-uniform

    // steady A-fragments: 5 tiles (4 gate quarters + proj) x 3 K-chunks
    FragU A[5][3];
    #pragma unroll
    for (int t = 0; t < 5; ++t)
        #pragma unroll
        for (int c = 0; c < 3; ++c)
            A[t][c].u = *reinterpret_cast<const u32x4*>(ws + ((t * 3 + c) * 64 + lane) * 4);

    // bias B-chunk: logical k=32 (steady) / k=48 (step0) at (hi=0, v=0, lo half)
    FragU Bbias;
    Bbias.u.x = (hi == 0) ? 0x3F80u : 0u;  // bf16(1.0)
    Bbias.u.y = 0u; Bbias.u.z = 0u; Bbias.u.w = 0u;

    // cell state in D-layout: cc[r] <-> c[bg][(r&3) + 8*(r>>2) + 4*hi]
    float cc[16];
    #pragma unroll
    for (int q = 0; q < 4; ++q) {
        f32x4 t = *reinterpret_cast<const f32x4*>(c0 + (size_t)bg * H + q * 8 + 4 * hi);
        cc[q * 4 + 0] = t.x; cc[q * 4 + 1] = t.y; cc[q * 4 + 2] = t.z; cc[q * 4 + 3] = t.w;
    }

    const f32x16 vzero = {};
    f32x16 acc[4];
    FragU Bh[2];

    // ---- step-0 gates: K = [x0(16) | h0(32) | 1], W0_aug fragments ----
    {
        FragU B0[4];
        {
            const float* p = x0 + (size_t)bg * P;
            f32x4 a  = *reinterpret_cast<const f32x4*>(p + 4 * hi);
            f32x4 b4 = *reinterpret_cast<const f32x4*>(p + 8 + 4 * hi);
            B0[0].u.x = pkbf(a.x, a.y);  B0[0].u.y = pkbf(a.z, a.w);
            B0[0].u.z = pkbf(b4.x, b4.y); B0[0].u.w = pkbf(b4.z, b4.w);
        }
        #pragma unroll
        for (int ch = 0; ch < 2; ++ch) {
            const float* p = h0 + (size_t)bg * H + 16 * ch;
            f32x4 a  = *reinterpret_cast<const f32x4*>(p + 4 * hi);
            f32x4 b4 = *reinterpret_cast<const f32x4*>(p + 8 + 4 * hi);
            B0[1 + ch].u.x = pkbf(a.x, a.y);  B0[1 + ch].u.y = pkbf(a.z, a.w);
            B0[1 + ch].u.z = pkbf(b4.x, b4.y); B0[1 + ch].u.w = pkbf(b4.z, b4.w);
        }
        B0[3] = Bbias;

        #pragma unroll
        for (int t = 0; t < 4; ++t) acc[t] = vzero;
        #pragma unroll
        for (int c4 = 0; c4 < 4; ++c4) {
            #pragma unroll
            for (int t = 0; t < 4; ++t) {
                FragU a;
                a.u = *reinterpret_cast<const u32x4*>(ws + 3840 + ((t * 4 + c4) * 64 + lane) * 4);
                acc[t] = __builtin_amdgcn_mfma_f32_32x32x16_bf16(a.b, B0[c4].b, acc[t], 0, 0, 0);
            }
        }
    }

    // ---------------- per-step phases (compile-time indexed) --------------
    auto EWPACK = [&]() {
        float hh[16];
        #pragma unroll
        for (int r = 0; r < 16; ++r) {
            const float ei = EX2(acc[0][r]);        // e^{-i}
            const float ef = EX2(acc[1][r]);        // e^{-f}
            const float eg = EX2(acc[2][r]);        // e^{-2g}
            const float eo = EX2(acc[3][r]);        // e^{-o}
            const float r1 = __builtin_amdgcn_rcpf((1.0f + ei) * (1.0f + eg));
            const float tg = (1.0f - eg) * r1;      // sig(i)*tanh(g)
            const float rf = __builtin_amdgcn_rcpf(1.0f + ef);
            const float cn = __builtin_fmaf(cc[r], rf, tg);
            cc[r] = cn;
            const float ec = EX2(cn * -2.8853900817779268f);  // e^{-2cn}
            const float r2 = __builtin_amdgcn_rcpf((1.0f + ec) * (1.0f + eo));
            hh[r] = (1.0f - ec) * r2;               // sig(o)*tanh(cn)
        }
        Bh[0].u.x = pkbf(hh[0],  hh[1]);  Bh[0].u.y = pkbf(hh[2],  hh[3]);
        Bh[0].u.z = pkbf(hh[4],  hh[5]);  Bh[0].u.w = pkbf(hh[6],  hh[7]);
        Bh[1].u.x = pkbf(hh[8],  hh[9]);  Bh[1].u.y = pkbf(hh[10], hh[11]);
        Bh[1].u.z = pkbf(hh[12], hh[13]); Bh[1].u.w = pkbf(hh[14], hh[15]);
    };
    auto PROJ = [&](f32x4& v0, f32x4& v1) {
        f32x16 px;
        px = __builtin_amdgcn_mfma_f32_32x32x16_bf16(A[4][2].b, Bbias.b, vzero, 0, 0, 0);
        px = __builtin_amdgcn_mfma_f32_32x32x16_bf16(A[4][0].b, Bh[0].b, px,    0, 0, 0);
        px = __builtin_amdgcn_mfma_f32_32x32x16_bf16(A[4][1].b, Bh[1].b, px,    0, 0, 0);
        v0 = f32x4{px[0], px[1], px[2], px[3]};
        v1 = f32x4{px[4], px[5], px[6], px[7]};
    };
    auto GATES = [&]() {
        #pragma unroll
        for (int t = 0; t < 4; ++t) {
            f32x16 a;
            a = __builtin_amdgcn_mfma_f32_32x32x16_bf16(A[t][2].b, Bbias.b, vzero, 0, 0, 0);
            a = __builtin_amdgcn_mfma_f32_32x32x16_bf16(A[t][0].b, Bh[0].b, a,    0, 0, 0);
            a = __builtin_amdgcn_mfma_f32_32x32x16_bf16(A[t][1].b, Bh[1].b, a,    0, 0, 0);
            acc[t] = a;
        }
    };

    float* const o = out + (size_t)bg * (S * P) + 4 * hi;

    // 4-step projection buffer (dedicated regs, static indexing)
    f32x4 pa0, pb0, pa1, pb1, pa2, pb2, pa3, pb3;

    // ---- steady loop: 6 blocks of 4 steps + tail step 24 ----
    for (int blk = 0; blk < 6; ++blk) {
        EWPACK(); PROJ(pa0, pb0); GATES();
        EWPACK(); PROJ(pa1, pb1); GATES();
        EWPACK(); PROJ(pa2, pb2); GATES();
        EWPACK(); PROJ(pa3, pb3); GATES();
        // flush: per row a contiguous 256B run (4 steps x 64B), NT
        float* ob = o + blk * 4 * P;
        __builtin_nontemporal_store(pa0, reinterpret_cast<f32x4*>(ob));
        __builtin_nontemporal_store(pb0, reinterpret_cast<f32x4*>(ob + 8));
        __builtin_nontemporal_store(pa1, reinterpret_cast<f32x4*>(ob + P));
        __builtin_nontemporal_store(pb1, reinterpret_cast<f32x4*>(ob + P + 8));
        __builtin_nontemporal_store(pa2, reinterpret_cast<f32x4*>(ob + 2 * P));
        __builtin_nontemporal_store(pb2, reinterpret_cast<f32x4*>(ob + 2 * P + 8));
        __builtin_nontemporal_store(pa3, reinterpret_cast<f32x4*>(ob + 3 * P));
        __builtin_nontemporal_store(pb3, reinterpret_cast<f32x4*>(ob + 3 * P + 8));
    }
    // tail: step 24 (no next gates)
    EWPACK();
    PROJ(pa0, pb0);
    __builtin_nontemporal_store(pa0, reinterpret_cast<f32x4*>(o + 24 * P));
    __builtin_nontemporal_store(pb0, reinterpret_cast<f32x4*>(o + 24 * P + 8));
}

extern "C" void kernel_launch(void* const* d_in, const int* in_sizes, int n_in,
                              void* d_out, int out_size, void* d_ws, size_t ws_size,
                              hipStream_t stream) {
    const float* x0   = (const float*)d_in[0];
    const float* h0   = (const float*)d_in[1];
    const float* c0   = (const float*)d_in[2];
    const float* Wih  = (const float*)d_in[3];
    const float* Whh  = (const float*)d_in[4];
    const float* bih  = (const float*)d_in[5];
    const float* bhh  = (const float*)d_in[6];
    const float* Wout = (const float*)d_in[7];
    const float* bout = (const float*)d_in[8];
    float* out = (float*)d_out;
    unsigned int* ws = (unsigned int*)d_ws;

    const int batch = in_sizes[0] / P;  // 262144

    hipLaunchKernelGGL(setup_frags, dim3(1), dim3(256), 0, stream,
                       Wih, Whh, bih, bhh, Wout, bout, ws);

    dim3 block(256);                    // 4 waves x 32 batch rows = 128 batch/block
    dim3 grid((batch + 127) / 128);     // 2048 blocks
    hipLaunchKernelGGL(decoder_mfma, grid, block, 0, stream,
                       x0, h0, c0, ws, out, batch);
}